// Round 1
// baseline (119.270 us; speedup 1.0000x reference)
//
#include <hip/hip_runtime.h>
#include <hip/hip_bf16.h>
#include <stdint.h>

typedef __attribute__((ext_vector_type(8))) short short8;
typedef __attribute__((ext_vector_type(4))) float f32x4;
typedef uint32_t u32;
typedef uint16_t u16;

#define LOG2E 1.4426950408889634f

// B=4, N=2048, Cin=256, F=64, H=4
// ws layout (bytes):
//  adjw   : 0x000000  u32 [2048*64]           512KB  packed adjacency bits (row-major, bit j%32 of word [i][j/32])
//  hT     : 0x080000  bf16[16][64][2048]      4MB    h transposed per (b,h): [bh][f][n]
//  cat    : 0x480000  bf16[4][2048][256]      4MB    relu(hp) concat heads
//  f1a    : 0x880000  f32 [16][2048]          128KB  f1*log2e
//  f1b    : 0x8A0000  f32                      128KB  0.2*f1*log2e
//  f2a    : 0x8C0000  f32                      128KB  f2*log2e   (later += -log2 D)
//  f2b    : 0x8E0000  f32                      128KB  0.2*f2*log2e (later += -log2 D)
//  wa1    : 0x900000  f32 [4][256]            4KB    sum_f W[h,c,f]*a1[h,f]
//  wa2    : 0x901000  f32 [4][256]            4KB
//  WT     : 0x902000  bf16[4][64][256]        128KB  W transposed: [h][f][c]
//  Wlb    : 0x922000  bf16[64][256]           32KB   Wl as bf16
// total ~9.3MB

__device__ __forceinline__ u16 f2bf(float f){
  union{float f; u32 u;} x; x.f = f;
  u32 r = x.u + 0x7FFFu + ((x.u >> 16) & 1u);
  return (u16)(r >> 16);
}
__device__ __forceinline__ u32 pkbf(float a, float b){
  __hip_bfloat162 h = __float22bfloat162_rn(float2{a, b});
  union{ __hip_bfloat162 h; u32 u; } cv; cv.h = h;
  return cv.u;
}

// ---------------- K0: pack adj into bitmask ----------------
__global__ __launch_bounds__(256) void k_pack(const int* __restrict__ adj, u32* __restrict__ adjw){
  int t = blockIdx.x * 256 + threadIdx.x;      // element index over N*N
  int v = adj[t];
  unsigned long long m = __ballot(v > 0);
  int lane = threadIdx.x & 63;
  if (lane == 0)       adjw[t >> 5] = (u32)(m & 0xFFFFFFFFull);
  else if (lane == 32) adjw[t >> 5] = (u32)(m >> 32);
}

// ---------------- K0b: small precomputes ----------------
__global__ __launch_bounds__(256) void k_prep(const float* __restrict__ W, const float* __restrict__ a1,
                       const float* __restrict__ a2, const float* __restrict__ Wl,
                       float* __restrict__ wa1, float* __restrict__ wa2,
                       u16* __restrict__ WT, u16* __restrict__ Wlb){
  int t = blockIdx.x * 256 + threadIdx.x;      // grid 64 blocks -> 16384 threads
  if (t < 2048){
    int h = (t >> 8) & 3, c = t & 255;
    const float* av = (t < 1024) ? a1 : a2;
    float s = 0.f;
    #pragma unroll
    for (int f = 0; f < 64; f++) s += W[(h*256 + c)*64 + f] * av[h*64 + f];
    ((t < 1024) ? wa1 : wa2)[h*256 + c] = s;
  }
  for (int i = t; i < 4*64*256; i += 16384){
    int h = i >> 14, f = (i >> 8) & 63, c = i & 255;
    WT[i] = f2bf(W[(h*256 + c)*64 + f]);
  }
  for (int i = t; i < 64*256; i += 16384){
    Wlb[i] = f2bf(Wl[i]);
  }
}

// ---------------- K1: h = x @ W  (per head), writes hT[bh][f][n] bf16 ----------------
__global__ __launch_bounds__(256) void k_proj(const float* __restrict__ x,
                       const u16* __restrict__ WT, u16* __restrict__ hT){
  int rt = blockIdx.x;           // 128 row tiles of 64
  int cb = blockIdx.y;           // 4 col tiles of 64 (over h*64+f = 256 cols)
  int w = threadIdx.x >> 6, l = threadIdx.x & 63;
  int rA = rt*64 + w*16 + (l & 15);       // A-fragment row
  int kg = (l >> 4) * 8;
  f32x4 acc[4] = {};
  const float* xrow = x + (size_t)rA * 256;
  #pragma unroll
  for (int ks = 0; ks < 8; ks++){
    int c = ks*32 + kg;
    float4 xa = *(const float4*)(xrow + c);
    float4 xb = *(const float4*)(xrow + c + 4);
    union{u32 w[4]; short8 v;} A;
    A.w[0] = pkbf(xa.x, xa.y); A.w[1] = pkbf(xa.z, xa.w);
    A.w[2] = pkbf(xb.x, xb.y); A.w[3] = pkbf(xb.z, xb.w);
    #pragma unroll
    for (int q = 0; q < 4; q++){
      int col = cb*64 + q*16 + (l & 15);
      short8 Bf = *(const short8*)(WT + (size_t)col*256 + c);
      acc[q] = __builtin_amdgcn_mfma_f32_16x16x32_bf16(A.v, Bf, acc[q], 0, 0, 0);
    }
  }
  // store: D rows = rb+reg, col = cb*64 + q*16 + (l&15)
  int rb = rt*64 + w*16 + (l >> 4)*4;
  int b = rb >> 11, n = rb & 2047;
  #pragma unroll
  for (int q = 0; q < 4; q++){
    int fp = cb*64 + q*16 + (l & 15);    // (h,f) flat
    u32 p0 = pkbf(acc[q][0], acc[q][1]);
    u32 p1 = pkbf(acc[q][2], acc[q][3]);
    u16* dst = hT + ((size_t)(b*4 + (fp >> 6))*64 + (fp & 63))*2048 + n;
    *(uint2*)dst = uint2{p0, p1};
  }
}

// ---------------- K1.5: f1/f2 in exact fp32 via x @ wa ----------------
__global__ __launch_bounds__(256) void k_fdots(const float* __restrict__ x,
                       const float* __restrict__ wa1, const float* __restrict__ wa2,
                       float* __restrict__ f1a, float* __restrict__ f1b,
                       float* __restrict__ f2a, float* __restrict__ f2b){
  int w = threadIdx.x >> 6, l = threadIdx.x & 63;
  int r = blockIdx.x*4 + w;               // global row [0,8192)
  int b = r >> 11, n = r & 2047;
  float4 xv = *(const float4*)(x + (size_t)r*256 + l*4);
  #pragma unroll
  for (int h = 0; h < 4; h++){
    float4 w1 = *(const float4*)(wa1 + h*256 + l*4);
    float4 w2 = *(const float4*)(wa2 + h*256 + l*4);
    float p1 = xv.x*w1.x + xv.y*w1.y + xv.z*w1.z + xv.w*w1.w;
    float p2 = xv.x*w2.x + xv.y*w2.y + xv.z*w2.z + xv.w*w2.w;
    #pragma unroll
    for (int m = 32; m > 0; m >>= 1){ p1 += __shfl_xor(p1, m); p2 += __shfl_xor(p2, m); }
    if (l == 0){
      int o = (b*4 + h)*2048 + n;
      f1a[o] = p1 * LOG2E;           f1b[o] = p1 * (0.2f*LOG2E);
      f2a[o] = p2 * LOG2E;           f2b[o] = p2 * (0.2f*LOG2E);
    }
  }
}

// ---------------- K2: D[j] = sum_i masked exp; fold -log2(D) into f2a/f2b ----------------
__global__ __launch_bounds__(256) void k_colsum(const u32* __restrict__ adjw,
                       const float* __restrict__ f1a, const float* __restrict__ f1b,
                       float* __restrict__ f2a, float* __restrict__ f2b){
  int jt = blockIdx.x;      // 32 tiles of 64 j
  int bh = blockIdx.y;      // 16
  int w = threadIdx.x >> 6, l = threadIdx.x & 63;
  int j = jt*64 + l;
  const float* f1a_r = f1a + bh*2048;
  const float* f1b_r = f1b + bh*2048;
  float fa = f2a[bh*2048 + j];
  float fb = f2b[bh*2048 + j];
  int wi = jt*2 + (l >> 5);
  int sh = l & 31;
  float acc = 0.f;
  int i0 = w * 512;
  #pragma unroll 4
  for (int i = i0; i < i0 + 512; i++){
    float s1a = f1a_r[i], s1b = f1b_r[i];
    u32 wrd = adjw[i*64 + wi];
    float lg = fmaxf(s1a + fa, s1b + fb);
    float ev = __builtin_amdgcn_exp2f(lg);
    float bit = (float)((wrd >> sh) & 1u);
    acc = fmaf(ev, bit, acc);
  }
  __shared__ float part[4][64];
  part[w][l] = acc;
  __syncthreads();
  if (threadIdx.x < 64){
    float D = part[0][l] + part[1][l] + part[2][l] + part[3][l];
    float g2 = -__builtin_amdgcn_logf(D);
    f2a[bh*2048 + j] = fa + g2;
    f2b[bh*2048 + j] = fb + g2;
  }
}

// ---------------- K3: fused PV: hp = P @ h, relu, write cat ----------------
__global__ __launch_bounds__(256) void k_pv(const u32* __restrict__ adjw, const u16* __restrict__ hT,
                       const float* __restrict__ f1a, const float* __restrict__ f1b,
                       const float* __restrict__ f2a, const float* __restrict__ f2b,
                       u16* __restrict__ cat){
  int it = blockIdx.x;           // 32 i-tiles of 64
  int bh = blockIdx.y;           // 16
  int b = bh >> 2, h = bh & 3;
  int w = threadIdx.x >> 6, l = threadIdx.x & 63;

  __shared__ u32 maskw[64*68];        // padded stride 68 words (bank spread)
  __shared__ u16 hTl[64*136];         // [f][j] padded stride 136 bf16
  __shared__ float f2al[128], f2bl[128];

  {  // load mask strip: 64 rows x 64 words, once per block
    int row = threadIdx.x >> 2, seg = (threadIdx.x & 3) * 16;
    const u32* src = adjw + (size_t)(it*64 + row)*64 + seg;
    u32* d = maskw + row*68 + seg;
    *(uint4*)(d)      = *(const uint4*)(src);
    *(uint4*)(d + 4)  = *(const uint4*)(src + 4);
    *(uint4*)(d + 8)  = *(const uint4*)(src + 8);
    *(uint4*)(d + 12) = *(const uint4*)(src + 12);
  }

  int i_l = it*64 + w*16 + (l & 15);
  float f1a_l = f1a[bh*2048 + i_l];
  float f1b_l = f1b[bh*2048 + i_l];
  const float* f2a_row = f2a + bh*2048;
  const float* f2b_row = f2b + bh*2048;
  const u16* hTrow = hT + (size_t)bh * 64 * 2048;
  int kg = (l >> 4) * 8;
  f32x4 acc[4] = {};

  for (int jc = 0; jc < 2048; jc += 128){
    __syncthreads();
    {  // stage hT tile [64 f][128 j] + f2 slices
      int f = threadIdx.x >> 2, seg = (threadIdx.x & 3) * 32;
      const u16* src = hTrow + (size_t)f*2048 + jc + seg;
      u16* d = hTl + f*136 + seg;
      *(uint4*)(d)      = *(const uint4*)(src);
      *(uint4*)(d + 8)  = *(const uint4*)(src + 8);
      *(uint4*)(d + 16) = *(const uint4*)(src + 16);
      *(uint4*)(d + 24) = *(const uint4*)(src + 24);
      if (threadIdx.x < 64)       *(float2*)&f2al[threadIdx.x*2] = *(const float2*)(f2a_row + jc + threadIdx.x*2);
      else if (threadIdx.x < 128) { int t2 = threadIdx.x - 64; *(float2*)&f2bl[t2*2] = *(const float2*)(f2b_row + jc + t2*2); }
    }
    __syncthreads();
    #pragma unroll
    for (int ks = 0; ks < 4; ks++){
      float fa[8], fb[8];
      *(float4*)(fa)     = *(const float4*)&f2al[ks*32 + kg];
      *(float4*)(fa + 4) = *(const float4*)&f2al[ks*32 + kg + 4];
      *(float4*)(fb)     = *(const float4*)&f2bl[ks*32 + kg];
      *(float4*)(fb + 4) = *(const float4*)&f2bl[ks*32 + kg + 4];
      u32 wrd = maskw[(w*16 + (l & 15))*68 + (jc >> 5) + ks];
      float wv[8];
      #pragma unroll
      for (int e = 0; e < 8; e++){
        float lg = fmaxf(f1a_l + fa[e], f1b_l + fb[e]);
        float ev = __builtin_amdgcn_exp2f(lg);
        float bit = (float)((wrd >> (kg + e)) & 1u);
        wv[e] = ev * bit;
      }
      union{u32 w[4]; short8 v;} A;
      A.w[0] = pkbf(wv[0], wv[1]); A.w[1] = pkbf(wv[2], wv[3]);
      A.w[2] = pkbf(wv[4], wv[5]); A.w[3] = pkbf(wv[6], wv[7]);
      #pragma unroll
      for (int q = 0; q < 4; q++){
        const short8* bp = (const short8*)&hTl[(q*16 + (l & 15))*136 + ks*32 + kg];
        acc[q] = __builtin_amdgcn_mfma_f32_16x16x32_bf16(A.v, *bp, acc[q], 0, 0, 0);
      }
    }
  }
  // epilogue: relu, store cat[b][n][h*64+f] bf16
  int nb = it*64 + w*16 + (l >> 4)*4;
  #pragma unroll
  for (int q = 0; q < 4; q++){
    int f = q*16 + (l & 15);
    #pragma unroll
    for (int r = 0; r < 4; r++){
      float v = fmaxf(acc[q][r], 0.f);
      cat[((size_t)(b*2048 + nb + r))*256 + h*64 + f] = f2bf(v);
    }
  }
}

// ---------------- K4: out = leaky(cat @ Wl^T + bl) ----------------
__global__ __launch_bounds__(256) void k_out(const u16* __restrict__ cat,
                       const u16* __restrict__ Wlb, const float* __restrict__ bl,
                       float* __restrict__ out){
  int rt = blockIdx.x;   // 128 row tiles
  int w = threadIdx.x >> 6, l = threadIdx.x & 63;
  int rA = rt*64 + w*16 + (l & 15);
  int kg = (l >> 4) * 8;
  f32x4 acc[4] = {};
  #pragma unroll
  for (int ks = 0; ks < 8; ks++){
    int c = ks*32 + kg;
    short8 Af = *(const short8*)(cat + (size_t)rA*256 + c);
    #pragma unroll
    for (int q = 0; q < 4; q++){
      short8 Bf = *(const short8*)(Wlb + (size_t)(q*16 + (l & 15))*256 + c);
      acc[q] = __builtin_amdgcn_mfma_f32_16x16x32_bf16(Af, Bf, acc[q], 0, 0, 0);
    }
  }
  int rb = rt*64 + w*16 + (l >> 4)*4;
  #pragma unroll
  for (int q = 0; q < 4; q++){
    int o = q*16 + (l & 15);
    float bv = bl[o];
    #pragma unroll
    for (int r = 0; r < 4; r++){
      float v = acc[q][r] + bv;
      out[(size_t)(rb + r)*64 + o] = fmaxf(v, 0.2f*v);
    }
  }
}

extern "C" void kernel_launch(void* const* d_in, const int* in_sizes, int n_in,
                              void* d_out, int out_size, void* d_ws, size_t ws_size,
                              hipStream_t stream) {
  const float* x  = (const float*)d_in[0];
  const int* adj  = (const int*)d_in[1];
  const float* W  = (const float*)d_in[2];
  const float* a1 = (const float*)d_in[3];
  const float* a2 = (const float*)d_in[4];
  const float* Wl = (const float*)d_in[5];
  const float* bl = (const float*)d_in[6];
  float* out = (float*)d_out;
  char* ws = (char*)d_ws;

  u32* adjw = (u32*)(ws + 0x000000);
  u16* hT   = (u16*)(ws + 0x080000);
  u16* cat  = (u16*)(ws + 0x480000);
  float* f1a = (float*)(ws + 0x880000);
  float* f1b = (float*)(ws + 0x8A0000);
  float* f2a = (float*)(ws + 0x8C0000);
  float* f2b = (float*)(ws + 0x8E0000);
  float* wa1 = (float*)(ws + 0x900000);
  float* wa2 = (float*)(ws + 0x901000);
  u16* WT    = (u16*)(ws + 0x902000);
  u16* Wlb   = (u16*)(ws + 0x922000);

  k_pack<<<16384, 256, 0, stream>>>(adj, adjw);
  k_prep<<<64, 256, 0, stream>>>(W, a1, a2, Wl, wa1, wa2, WT, Wlb);
  k_proj<<<dim3(128, 4), 256, 0, stream>>>(x, WT, hT);
  k_fdots<<<2048, 256, 0, stream>>>(x, wa1, wa2, f1a, f1b, f2a, f2b);
  k_colsum<<<dim3(32, 16), 256, 0, stream>>>(adjw, f1a, f1b, f2a, f2b);
  k_pv<<<dim3(32, 16), 256, 0, stream>>>(adjw, hT, f1a, f1b, f2a, f2b, cat);
  k_out<<<128, 256, 0, stream>>>(cat, Wlb, bl, out);
}